// Round 8
// baseline (143.317 us; speedup 1.0000x reference)
//
#include <hip/hip_runtime.h>
#include <hip/hip_bf16.h>

typedef __bf16 bf16x8 __attribute__((ext_vector_type(8)));
typedef __bf16 bf16x4 __attribute__((ext_vector_type(4)));
typedef float  f32x4  __attribute__((ext_vector_type(4)));

#define NB 64
#define LL 1024
#define DD 64
#define PSTR 36   // fp32 stride for Pw rows (kernel B)
#define PS 516    // bf16 stride for Pdb rows (kernel C)

#define B_LDS (LL * DD * 2 + 8 * 16 * PSTR * 4)          // 128K + 18K
#define C_LDS (LL * DD * 2 + 2 * 8 * PS * 2)             // 128K + 16.1K = 147584

#define WS_VT_OFF 0
#define WS_RL_OFF ((size_t)8 * 1024 * 1024)
#define WS_NEED   (WS_RL_OFF + (size_t)NB * LL * 4)

#if __has_builtin(__builtin_amdgcn_exp2f)
#define EXP2(x) __builtin_amdgcn_exp2f(x)
#else
#define EXP2(x) exp2f(x)
#endif

// raw barrier: lgkm-fenced, does NOT drain the store queue (unlike __syncthreads)
#define PHASE_BARRIER() do {                                   \
  __builtin_amdgcn_sched_barrier(0);                           \
  asm volatile("s_waitcnt lgkmcnt(0)" ::: "memory");           \
  __builtin_amdgcn_s_barrier();                                \
  __builtin_amdgcn_sched_barrier(0);                           \
} while (0)

// ---------------- V pre-pass: transpose+convert V -> Vt bf16 [b][d][key] ----
__global__ __launch_bounds__(256)
void preconvert_v(const float* __restrict__ v, __bf16* __restrict__ vt) {
  const int blk = blockIdx.x, tid = threadIdx.x;
  const int b = blk >> 4, t = blk & 15;
  __shared__ float tile[64][65];
  const float* src = v + ((size_t)b * LL + t * 64) * DD;
  for (int i = tid; i < 64 * 16; i += 256) {
    const int row = i >> 4, c4 = (i & 15) * 4;
    f32x4 x = *(const f32x4*)(src + row * DD + c4);
    tile[row][c4 + 0] = x[0]; tile[row][c4 + 1] = x[1];
    tile[row][c4 + 2] = x[2]; tile[row][c4 + 3] = x[3];
  }
  __syncthreads();
  __bf16* dst = vt + (size_t)b * DD * LL + t * 64;
  for (int i = tid; i < 64 * 8; i += 256) {
    const int d = i >> 3, k8 = (i & 7) * 8;
    bf16x8 o;
    #pragma unroll
    for (int j = 0; j < 8; ++j) o[j] = (__bf16)tile[k8 + j][d];
    *(bf16x8*)(dst + (size_t)d * LL + k8) = o;
  }
}

// ------- kernel B: whole-K LDS, denominators + PV + ctx (NO attn stores) ----
__global__ __launch_bounds__(512, 1)
void sdpa_nostore(const float* __restrict__ q, const float* __restrict__ kf,
                  const __bf16* __restrict__ vt, const float* __restrict__ scale_p,
                  float* __restrict__ rlbuf, float* __restrict__ out) {
  extern __shared__ char smem[];
  __bf16* Klds = (__bf16*)smem;                     // [1024][64], XOR-swizzled
  float*  Pw   = (float*)(smem + LL * DD * 2);      // [8][16][PSTR]

  const int tid  = threadIdx.x;
  const int lane = tid & 63;
  const int w    = tid >> 6;
  const int l15  = lane & 15;
  const int lg   = lane >> 4;

  int bid = blockIdx.x;
  bid = (bid & 7) * 32 + (bid >> 3);
  const int b     = bid >> 2;
  const int qrow0 = (bid & 3) * 256 + w * 32;

  const float scale2 = scale_p[0] * 1.4426950408889634f;
  const float* kb  = kf + (size_t)b * LL * DD;
  const __bf16* vb = vt + (size_t)b * DD * LL;
  float* ctxb = out + ((size_t)b * LL + qrow0) * DD;

  #pragma unroll
  for (int it = 0; it < 16; ++it) {
    const int c = it * 512 + tid;
    const int row = c >> 3, slot = c & 7;
    const f32x4* s4 = (const f32x4*)(kb + (size_t)c * 8);
    f32x4 x0 = s4[0], x1 = s4[1];
    bf16x8 t;
    #pragma unroll
    for (int j = 0; j < 4; ++j) { t[j] = (__bf16)x0[j]; t[4 + j] = (__bf16)x1[j]; }
    *(bf16x8*)(Klds + row * 64 + ((slot * 8) ^ ((row & 7) * 8))) = t;
  }

  bf16x8 aq[2][2];
  #pragma unroll
  for (int u = 0; u < 2; ++u) {
    const float* qrow = q + ((size_t)b * LL + qrow0 + u * 16 + l15) * DD;
    #pragma unroll
    for (int s = 0; s < 2; ++s) {
      const f32x4* p4 = (const f32x4*)(qrow + s * 32 + lg * 8);
      f32x4 x0 = p4[0], x1 = p4[1];
      #pragma unroll
      for (int j = 0; j < 4; ++j) {
        aq[u][s][j]     = (__bf16)(x0[j] * scale2);
        aq[u][s][4 + j] = (__bf16)(x1[j] * scale2);
      }
    }
  }

  __syncthreads();

  const int xsw = (l15 & 7) * 8;

  // pass 1: denominators
  float ls[2] = {0.f, 0.f};
  for (int kt = 0; kt < 32; ++kt) {
    bf16x8 bk[2][2];
    #pragma unroll
    for (int f = 0; f < 2; ++f)
      #pragma unroll
      for (int s = 0; s < 2; ++s)
        bk[f][s] = *(const bf16x8*)(Klds + (kt * 32 + f * 16 + l15) * 64
                                         + ((s * 32 + lg * 8) ^ xsw));
    #pragma unroll
    for (int u = 0; u < 2; ++u) {
      f32x4 sacc[2] = {{0.f,0.f,0.f,0.f},{0.f,0.f,0.f,0.f}};
      #pragma unroll
      for (int s = 0; s < 2; ++s)
        #pragma unroll
        for (int f = 0; f < 2; ++f)
          sacc[f] = __builtin_amdgcn_mfma_f32_16x16x32_bf16(bk[f][s], aq[u][s], sacc[f], 0, 0, 0);
      #pragma unroll
      for (int f = 0; f < 2; ++f)
        #pragma unroll
        for (int r = 0; r < 4; ++r)
          ls[u] += EXP2(sacc[f][r]);
    }
  }
  #pragma unroll
  for (int u = 0; u < 2; ++u) {
    ls[u] += __shfl_xor(ls[u], 16, 64);
    ls[u] += __shfl_xor(ls[u], 32, 64);
  }
  const float rl[2] = {1.0f / ls[0], 1.0f / ls[1]};
  if (lg == 0) {
    float* rp = rlbuf + (size_t)b * LL + qrow0 + l15;
    rp[0]  = rl[0];
    rp[16] = rl[1];
  }

  // pass 2: PV only (no attention stores)
  f32x4 cacc[2][4];
  #pragma unroll
  for (int u = 0; u < 2; ++u)
    #pragma unroll
    for (int g = 0; g < 4; ++g)
      cacc[u][g] = (f32x4){0.f, 0.f, 0.f, 0.f};

  float* prow = Pw + (w * 16 + l15) * PSTR;

  bf16x8 bvn[4];
  #pragma unroll
  for (int g = 0; g < 4; ++g)
    bvn[g] = *(const bf16x8*)(vb + (size_t)(g * 16 + l15) * LL + lg * 8);

  for (int kt = 0; kt < 32; ++kt) {
    bf16x8 bvc[4];
    #pragma unroll
    for (int g = 0; g < 4; ++g) bvc[g] = bvn[g];
    if (kt + 1 < 32) {
      #pragma unroll
      for (int g = 0; g < 4; ++g)
        bvn[g] = *(const bf16x8*)(vb + (size_t)(g * 16 + l15) * LL
                                     + (kt + 1) * 32 + lg * 8);
    }
    bf16x8 bk[2][2];
    #pragma unroll
    for (int f = 0; f < 2; ++f)
      #pragma unroll
      for (int s = 0; s < 2; ++s)
        bk[f][s] = *(const bf16x8*)(Klds + (kt * 32 + f * 16 + l15) * 64
                                         + ((s * 32 + lg * 8) ^ xsw));
    #pragma unroll
    for (int u = 0; u < 2; ++u) {
      f32x4 sacc[2] = {{0.f,0.f,0.f,0.f},{0.f,0.f,0.f,0.f}};
      #pragma unroll
      for (int s = 0; s < 2; ++s)
        #pragma unroll
        for (int f = 0; f < 2; ++f)
          sacc[f] = __builtin_amdgcn_mfma_f32_16x16x32_bf16(bk[f][s], aq[u][s], sacc[f], 0, 0, 0);
      #pragma unroll
      for (int f = 0; f < 2; ++f) {
        f32x4 pv;
        #pragma unroll
        for (int r = 0; r < 4; ++r)
          pv[r] = EXP2(sacc[f][r]) * rl[u];
        *(f32x4*)(prow + f * 16 + lg * 4) = pv;
      }
      f32x4 p0 = *(const f32x4*)(prow + lg * 8);
      f32x4 p1 = *(const f32x4*)(prow + lg * 8 + 4);
      bf16x8 pa;
      #pragma unroll
      for (int j = 0; j < 4; ++j) { pa[j] = (__bf16)p0[j]; pa[4 + j] = (__bf16)p1[j]; }
      #pragma unroll
      for (int g = 0; g < 4; ++g)
        cacc[u][g] = __builtin_amdgcn_mfma_f32_16x16x32_bf16(pa, bvc[g], cacc[u][g], 0, 0, 0);
    }
  }

  #pragma unroll
  for (int u = 0; u < 2; ++u)
    #pragma unroll
    for (int g = 0; g < 4; ++g)
      #pragma unroll
      for (int r = 0; r < 4; ++r)
        ctxb[(size_t)(u * 16 + lg * 4 + r) * DD + g * 16 + l15] = cacc[u][g][r];
}

// ------- kernel C: contiguous full-row attention stores ---------------------
__global__ __launch_bounds__(512, 1)
void sdpa_cstore(const float* __restrict__ q, const float* __restrict__ kf,
                 const float* __restrict__ rlbuf, const float* __restrict__ scale_p,
                 float* __restrict__ out) {
  extern __shared__ char smem[];
  __bf16* Klds = (__bf16*)smem;                        // [1024][64] swizzled
  __bf16* Pdb  = (__bf16*)(smem + LL * DD * 2);        // [2][8][PS]

  const int tid  = threadIdx.x;
  const int lane = tid & 63;
  const int w    = tid >> 6;
  const int l15  = lane & 15;
  const int lg   = lane >> 4;
  const int qr   = l15 & 7;            // duplicated q-row index within chunk

  int bid = blockIdx.x;
  bid = (bid & 7) * 32 + (bid >> 3);
  const int b     = bid >> 2;
  const int qrow0 = (bid & 3) * 256;

  const float scale2 = scale_p[0] * 1.4426950408889634f;
  const float* kb = kf + (size_t)b * LL * DD;
  float* attnb = out + (size_t)NB * LL * DD + (size_t)b * LL * LL
               + (size_t)qrow0 * LL;

  // stage all K: fp32 -> bf16 LDS, swizzled
  #pragma unroll
  for (int it = 0; it < 16; ++it) {
    const int c = it * 512 + tid;
    const int row = c >> 3, slot = c & 7;
    const f32x4* s4 = (const f32x4*)(kb + (size_t)c * 8);
    f32x4 x0 = s4[0], x1 = s4[1];
    bf16x8 t;
    #pragma unroll
    for (int j = 0; j < 4; ++j) { t[j] = (__bf16)x0[j]; t[4 + j] = (__bf16)x1[j]; }
    *(bf16x8*)(Klds + row * 64 + ((slot * 8) ^ ((row & 7) * 8))) = t;
  }

  const float* qbase  = q + ((size_t)b * LL + qrow0 + qr) * DD;
  const float* rlbase = rlbuf + (size_t)b * LL + qrow0 + qr;

  // prefetch chunk-0 operands
  f32x4 qn[4];
  #pragma unroll
  for (int t2 = 0; t2 < 2; ++t2) {
    qn[2 * t2]     = *(const f32x4*)(qbase + t2 * 32 + lg * 8);
    qn[2 * t2 + 1] = *(const f32x4*)(qbase + t2 * 32 + lg * 8 + 4);
  }
  float rln = rlbase[0];

  __syncthreads();   // K resident (full drain OK here, nothing material in flight)

  const int xsw = qr * 8;
  int cur = 0;
  bf16x8 aq[2];
  float rl = 0.f;

  for (int p = 0; p < 64; ++p) {
    const int c = p >> 1, hk = p & 1;

    if (hk == 0) {   // commit prefetched Q/rl (uniform branch)
      #pragma unroll
      for (int s = 0; s < 2; ++s)
        #pragma unroll
        for (int j = 0; j < 4; ++j) {
          aq[s][j]     = (__bf16)(qn[2 * s][j] * scale2);
          aq[s][4 + j] = (__bf16)(qn[2 * s + 1][j] * scale2);
        }
      rl = rln;
    }

    // compute: 2 kt tiles -> Pdb[cur] (8 rows x 512 keys across the block)
    __bf16* pb = Pdb + cur * (8 * PS) + qr * PS;
    #pragma unroll
    for (int i = 0; i < 2; ++i) {
      const int ktl = 2 * w + i;
      const int kt  = hk * 16 + ktl;
      bf16x8 bk[2][2];
      #pragma unroll
      for (int f = 0; f < 2; ++f)
        #pragma unroll
        for (int s = 0; s < 2; ++s)
          bk[f][s] = *(const bf16x8*)(Klds + (kt * 32 + f * 16 + l15) * 64
                                           + ((s * 32 + lg * 8) ^ xsw));
      f32x4 sacc[2] = {{0.f,0.f,0.f,0.f},{0.f,0.f,0.f,0.f}};
      #pragma unroll
      for (int s = 0; s < 2; ++s)
        #pragma unroll
        for (int f = 0; f < 2; ++f)
          sacc[f] = __builtin_amdgcn_mfma_f32_16x16x32_bf16(bk[f][s], aq[s], sacc[f], 0, 0, 0);
      #pragma unroll
      for (int f = 0; f < 2; ++f) {
        bf16x4 pv;
        #pragma unroll
        for (int r = 0; r < 4; ++r)
          pv[r] = (__bf16)(EXP2(sacc[f][r]) * rl);
        *(bf16x4*)(pb + ktl * 32 + f * 16 + lg * 4) = pv;
      }
    }

    // prefetch next chunk's Q/rl two phases ahead of use (keeps stores unwaited)
    if (hk == 0 && c + 1 < 32) {
      const float* qc = qbase + (size_t)(c + 1) * 8 * DD;
      #pragma unroll
      for (int t2 = 0; t2 < 2; ++t2) {
        qn[2 * t2]     = *(const f32x4*)(qc + t2 * 32 + lg * 8);
        qn[2 * t2 + 1] = *(const f32x4*)(qc + t2 * 32 + lg * 8 + 4);
      }
      rln = rlbase[(c + 1) * 8];
    }

    PHASE_BARRIER();

    // store: wave w streams row (c*8+w), cols [hk*512, hk*512+512) as 2x1KB
    {
      const __bf16* pr = Pdb + cur * (8 * PS) + w * PS;
      float* arow = attnb + (size_t)(c * 8 + w) * LL + hk * 512;
      #pragma unroll
      for (int j = 0; j < 2; ++j) {
        const uint2 rw = *(const uint2*)(pr + j * 256 + lane * 4);
        f32x4 o;
        o[0] = __uint_as_float(rw.x << 16);
        o[1] = __uint_as_float(rw.x & 0xffff0000u);
        o[2] = __uint_as_float(rw.y << 16);
        o[3] = __uint_as_float(rw.y & 0xffff0000u);
        *(f32x4*)(arow + j * 256 + lane * 4) = o;
      }
    }
    cur ^= 1;
  }
}

// ====================== fallback (R1 kernel, proven) ========================
#define BQ 64
#define BK 32
#define KSTRIDE 72
#define VSTRIDE 40
#define PSTRIDE 48

__global__ __launch_bounds__(256, 4)
void sdpa_fallback(const float* __restrict__ q, const float* __restrict__ k,
                   const float* __restrict__ v, const float* __restrict__ scale_p,
                   float* __restrict__ out) {
  const int tid  = threadIdx.x;
  const int lane = tid & 63;
  const int w    = tid >> 6;
  int bid = blockIdx.x;
  bid = (bid & 7) * 128 + (bid >> 3);
  const int b    = bid >> 4;
  const int qblk = (bid & 15) * BQ;

  __shared__ __bf16 Ks[BK * KSTRIDE];
  __shared__ __bf16 Vs[DD * VSTRIDE];
  __shared__ __bf16 Pp[4][16 * PSTRIDE];

  const float scale = scale_p[0];
  const float* qb = q + ((size_t)b * LL + qblk) * DD;
  const float* kb = k + (size_t)b * LL * DD;
  const float* vb = v + (size_t)b * LL * DD;
  float* ctx  = out + ((size_t)b * LL + qblk) * DD;
  float* attn = out + (size_t)NB * LL * DD + (size_t)b * LL * LL + (size_t)qblk * LL;

  const int l15 = lane & 15;
  const int lg  = lane >> 4;
  const int dchunk = lg * 8;

  bf16x8 aq[2];
  {
    const float* qrow = qb + (size_t)(w * 16 + l15) * DD;
    #pragma unroll
    for (int s = 0; s < 2; ++s) {
      const f32x4* p4 = (const f32x4*)(qrow + s * 32 + dchunk);
      f32x4 x0 = p4[0], x1 = p4[1];
      #pragma unroll
      for (int j = 0; j < 4; ++j) {
        aq[s][j]     = (__bf16)(x0[j] * scale);
        aq[s][4 + j] = (__bf16)(x1[j] * scale);
      }
    }
  }

  const int srow = tid >> 3;
  const int sd0  = (tid & 7) * 8;

  float lpart[4] = {0.f, 0.f, 0.f, 0.f};
  for (int kt = 0; kt < LL / BK; ++kt) {
    __syncthreads();
    {
      const f32x4* src = (const f32x4*)(kb + (size_t)(kt * BK + srow) * DD + sd0);
      f32x4 x0 = src[0], x1 = src[1];
      bf16x8 t;
      #pragma unroll
      for (int j = 0; j < 4; ++j) { t[j] = (__bf16)x0[j]; t[4 + j] = (__bf16)x1[j]; }
      *(bf16x8*)&Ks[srow * KSTRIDE + sd0] = t;
    }
    __syncthreads();
    f32x4 sacc[2] = {{0.f,0.f,0.f,0.f},{0.f,0.f,0.f,0.f}};
    #pragma unroll
    for (int s = 0; s < 2; ++s)
      #pragma unroll
      for (int f = 0; f < 2; ++f) {
        bf16x8 bk = *(const bf16x8*)&Ks[(f * 16 + l15) * KSTRIDE + s * 32 + dchunk];
        sacc[f] = __builtin_amdgcn_mfma_f32_16x16x32_bf16(aq[s], bk, sacc[f], 0, 0, 0);
      }
    #pragma unroll
    for (int f = 0; f < 2; ++f)
      #pragma unroll
      for (int r = 0; r < 4; ++r)
        lpart[r] += __expf(sacc[f][r]);
  }
  #pragma unroll
  for (int m = 1; m < 16; m <<= 1)
    #pragma unroll
    for (int r = 0; r < 4; ++r)
      lpart[r] += __shfl_xor(lpart[r], m, 64);
  float rl[4];
  #pragma unroll
  for (int r = 0; r < 4; ++r) rl[r] = 1.0f / lpart[r];

  f32x4 cacc[4] = {{0.f,0.f,0.f,0.f},{0.f,0.f,0.f,0.f},
                   {0.f,0.f,0.f,0.f},{0.f,0.f,0.f,0.f}};
  for (int kt = 0; kt < LL / BK; ++kt) {
    __syncthreads();
    {
      const f32x4* src = (const f32x4*)(kb + (size_t)(kt * BK + srow) * DD + sd0);
      f32x4 x0 = src[0], x1 = src[1];
      bf16x8 t;
      #pragma unroll
      for (int j = 0; j < 4; ++j) { t[j] = (__bf16)x0[j]; t[4 + j] = (__bf16)x1[j]; }
      *(bf16x8*)&Ks[srow * KSTRIDE + sd0] = t;
      const f32x4* vsrc = (const f32x4*)(vb + (size_t)(kt * BK + srow) * DD + sd0);
      f32x4 y0 = vsrc[0], y1 = vsrc[1];
      #pragma unroll
      for (int j = 0; j < 4; ++j) {
        Vs[(sd0 + j)     * VSTRIDE + srow] = (__bf16)y0[j];
        Vs[(sd0 + 4 + j) * VSTRIDE + srow] = (__bf16)y1[j];
      }
    }
    __syncthreads();
    f32x4 sacc[2] = {{0.f,0.f,0.f,0.f},{0.f,0.f,0.f,0.f}};
    #pragma unroll
    for (int s = 0; s < 2; ++s)
      #pragma unroll
      for (int f = 0; f < 2; ++f) {
        bf16x8 bk = *(const bf16x8*)&Ks[(f * 16 + l15) * KSTRIDE + s * 32 + dchunk];
        sacc[f] = __builtin_amdgcn_mfma_f32_16x16x32_bf16(aq[s], bk, sacc[f], 0, 0, 0);
      }
    #pragma unroll
    for (int f = 0; f < 2; ++f)
      #pragma unroll
      for (int r = 0; r < 4; ++r) {
        const int row = lg * 4 + r;
        float p = __expf(sacc[f][r]) * rl[r];
        attn[(size_t)(w * 16 + row) * LL + (kt * BK + f * 16 + l15)] = p;
        Pp[w][row * PSTRIDE + f * 16 + l15] = (__bf16)p;
      }
    bf16x8 pa = *(const bf16x8*)&Pp[w][l15 * PSTRIDE + lg * 8];
    #pragma unroll
    for (int g = 0; g < 4; ++g) {
      bf16x8 bv = *(const bf16x8*)&Vs[(g * 16 + l15) * VSTRIDE + lg * 8];
      cacc[g] = __builtin_amdgcn_mfma_f32_16x16x32_bf16(pa, bv, cacc[g], 0, 0, 0);
    }
  }
  #pragma unroll
  for (int g = 0; g < 4; ++g)
    #pragma unroll
    for (int r = 0; r < 4; ++r)
      ctx[(size_t)(w * 16 + lg * 4 + r) * DD + g * 16 + l15] = cacc[g][r];
}

extern "C" void kernel_launch(void* const* d_in, const int* in_sizes, int n_in,
                              void* d_out, int out_size, void* d_ws, size_t ws_size,
                              hipStream_t stream) {
  const float* q = (const float*)d_in[0];
  const float* k = (const float*)d_in[1];
  const float* v = (const float*)d_in[2];
  const float* s = (const float*)d_in[3];
  float* out = (float*)d_out;

  if (ws_size >= WS_NEED) {
    __bf16* vt = (__bf16*)((char*)d_ws + WS_VT_OFF);
    float*  rl = (float*)((char*)d_ws + WS_RL_OFF);
    preconvert_v<<<dim3(NB * (LL / 64)), dim3(256), 0, stream>>>(v, vt);
    (void)hipFuncSetAttribute((const void*)sdpa_nostore,
                              hipFuncAttributeMaxDynamicSharedMemorySize, B_LDS);
    sdpa_nostore<<<dim3(256), dim3(512), B_LDS, stream>>>(q, k, vt, s, rl, out);
    (void)hipFuncSetAttribute((const void*)sdpa_cstore,
                              hipFuncAttributeMaxDynamicSharedMemorySize, C_LDS);
    sdpa_cstore<<<dim3(256), dim3(512), C_LDS, stream>>>(q, k, rl, s, out);
  } else {
    sdpa_fallback<<<dim3(NB * (LL / 64)), dim3(256), 0, stream>>>(q, k, v, s, out);
  }
}

// Round 9
// 112.985 us; speedup vs baseline: 1.2685x; 1.2685x over previous
//
#include <hip/hip_runtime.h>
#include <hip/hip_bf16.h>

typedef __bf16 bf16x8 __attribute__((ext_vector_type(8)));
typedef __bf16 bf16x4 __attribute__((ext_vector_type(4)));
typedef float  f32x4  __attribute__((ext_vector_type(4)));

#define NB 64
#define LL 1024
#define DD 64
#define PB 40    // bf16 stride for P rows (80 B, R5-proven)

#define WS_VT_OFF 0
#define WS_KB_OFF ((size_t)8 * 1024 * 1024)
#define WS_NEED   ((size_t)16 * 1024 * 1024)

#if __has_builtin(__builtin_amdgcn_exp2f)
#define EXP2(x) __builtin_amdgcn_exp2f(x)
#else
#define EXP2(x) exp2f(x)
#endif

// ---------- prep: V -> Vt bf16 [b][d][key]  +  K -> bf16 [b][key][d] --------
__global__ __launch_bounds__(256)
void preconvert_kv(const float* __restrict__ k, const float* __restrict__ v,
                   __bf16* __restrict__ kbf, __bf16* __restrict__ vt) {
  const int blk = blockIdx.x, tid = threadIdx.x;
  if (blk < NB * (LL / 64)) {
    const int b = blk >> 4, t = blk & 15;   // 64-key tile t of batch b
    __shared__ float tile[64][65];
    const float* src = v + ((size_t)b * LL + t * 64) * DD;
    for (int i = tid; i < 64 * 16; i += 256) {
      const int row = i >> 4, c4 = (i & 15) * 4;
      f32x4 x = *(const f32x4*)(src + row * DD + c4);
      tile[row][c4 + 0] = x[0]; tile[row][c4 + 1] = x[1];
      tile[row][c4 + 2] = x[2]; tile[row][c4 + 3] = x[3];
    }
    __syncthreads();
    __bf16* dst = vt + (size_t)b * DD * LL + t * 64;
    for (int i = tid; i < 64 * 8; i += 256) {
      const int d = i >> 3, k8 = (i & 7) * 8;
      bf16x8 o;
      #pragma unroll
      for (int j = 0; j < 8; ++j) o[j] = (__bf16)tile[k8 + j][d];
      *(bf16x8*)(dst + (size_t)d * LL + k8) = o;
    }
  } else {
    const size_t base = ((size_t)(blk - 1024) * 256 + tid) * 8;
    const f32x4* s = (const f32x4*)(k + base);
    f32x4 x0 = s[0], x1 = s[1];
    bf16x8 o;
    #pragma unroll
    for (int j = 0; j < 4; ++j) { o[j] = (__bf16)x0[j]; o[4 + j] = (__bf16)x1[j]; }
    *(bf16x8*)(kbf + base) = o;
  }
}

// ---------- main: 4 blocks/CU, K quarters in LDS, fused pass1+pass2 ---------
__global__ __launch_bounds__(256, 4)
void sdpa_quarter(const float* __restrict__ q, const __bf16* __restrict__ kbf,
                  const __bf16* __restrict__ vt, const float* __restrict__ scale_p,
                  float* __restrict__ out) {
  __shared__ __bf16 Kq[256 * 64];        // 32 KB, XOR-swizzled quarter of K
  __shared__ __bf16 Pw[4 * 16 * PB];     // 5 KB wave-private P tiles

  const int tid  = threadIdx.x;
  const int lane = tid & 63;
  const int w    = tid >> 6;
  const int l15  = lane & 15;
  const int lg   = lane >> 4;

  int bid = blockIdx.x;                  // 1024 blocks, 1024 % 8 == 0
  bid = (bid & 7) * 128 + (bid >> 3);    // bijective XCD-chunk map
  const int b     = bid >> 4;
  const int qrow0 = (bid & 15) * 64 + w * 16;   // this wave's 16 q rows

  const float scale2 = scale_p[0] * 1.4426950408889634f;  // fold log2(e)
  const __bf16* kb = kbf + (size_t)b * LL * DD;
  const __bf16* vb = vt  + (size_t)b * DD * LL;
  float* ctxb  = out + ((size_t)b * LL + qrow0) * DD;
  float* attnb = out + (size_t)NB * LL * DD + (size_t)b * LL * LL
               + (size_t)qrow0 * LL;

  // ---- Q fragments (scale2 folded) ----
  bf16x8 aq[2];
  {
    const float* qrow = q + ((size_t)b * LL + qrow0 + l15) * DD;
    #pragma unroll
    for (int s = 0; s < 2; ++s) {
      const f32x4* p4 = (const f32x4*)(qrow + s * 32 + lg * 8);
      f32x4 x0 = p4[0], x1 = p4[1];
      #pragma unroll
      for (int j = 0; j < 4; ++j) {
        aq[s][j]     = (__bf16)(x0[j] * scale2);
        aq[s][4 + j] = (__bf16)(x1[j] * scale2);
      }
    }
  }

  const int xsw = (l15 & 7) * 8;
  __bf16* prow = Pw + (w * 16 + l15) * PB;

  // ================= pass 1: denominators over 4 K-quarters ================
  float ls = 0.f;
  for (int qt = 0; qt < 4; ++qt) {
    __syncthreads();
    #pragma unroll
    for (int it = 0; it < 8; ++it) {     // stage 256 keys (bf16, L2-resident)
      const int c = it * 256 + tid;      // 2048 chunks of 8 bf16
      const int row = c >> 3, slot = c & 7;
      bf16x8 t = *(const bf16x8*)(kb + (size_t)(qt * 256 + row) * 64 + slot * 8);
      *(bf16x8*)(Kq + row * 64 + ((slot * 8) ^ ((row & 7) * 8))) = t;
    }
    __syncthreads();
    for (int kt = 0; kt < 8; ++kt) {
      bf16x8 bk[2][2];
      #pragma unroll
      for (int f = 0; f < 2; ++f)
        #pragma unroll
        for (int s = 0; s < 2; ++s)
          bk[f][s] = *(const bf16x8*)(Kq + (kt * 32 + f * 16 + l15) * 64
                                         + ((s * 32 + lg * 8) ^ xsw));
      f32x4 sacc[2] = {{0.f,0.f,0.f,0.f},{0.f,0.f,0.f,0.f}};
      #pragma unroll
      for (int s = 0; s < 2; ++s)
        #pragma unroll
        for (int f = 0; f < 2; ++f)
          sacc[f] = __builtin_amdgcn_mfma_f32_16x16x32_bf16(bk[f][s], aq[s], sacc[f], 0, 0, 0);
      #pragma unroll
      for (int f = 0; f < 2; ++f)
        #pragma unroll
        for (int r = 0; r < 4; ++r)
          ls += EXP2(sacc[f][r]);
    }
  }
  ls += __shfl_xor(ls, 16, 64);
  ls += __shfl_xor(ls, 32, 64);
  const float rl = 1.0f / ls;

  // ================= pass 2: recompute, store attn, PV =====================
  f32x4 cacc[4];
  #pragma unroll
  for (int g = 0; g < 4; ++g) cacc[g] = (f32x4){0.f, 0.f, 0.f, 0.f};

  for (int qt = 0; qt < 4; ++qt) {
    __syncthreads();
    #pragma unroll
    for (int it = 0; it < 8; ++it) {
      const int c = it * 256 + tid;
      const int row = c >> 3, slot = c & 7;
      bf16x8 t = *(const bf16x8*)(kb + (size_t)(qt * 256 + row) * 64 + slot * 8);
      *(bf16x8*)(Kq + row * 64 + ((slot * 8) ^ ((row & 7) * 8))) = t;
    }
    __syncthreads();

    for (int kt = 0; kt < 8; ++kt) {
      // V fragments straight from L2-resident vt (issued early, hide under QK)
      bf16x8 bv[4];
      #pragma unroll
      for (int g = 0; g < 4; ++g)
        bv[g] = *(const bf16x8*)(vb + (size_t)(g * 16 + l15) * LL
                                    + qt * 256 + kt * 32 + lg * 8);

      bf16x8 bk[2][2];
      #pragma unroll
      for (int f = 0; f < 2; ++f)
        #pragma unroll
        for (int s = 0; s < 2; ++s)
          bk[f][s] = *(const bf16x8*)(Kq + (kt * 32 + f * 16 + l15) * 64
                                         + ((s * 32 + lg * 8) ^ xsw));

      f32x4 sacc[2] = {{0.f,0.f,0.f,0.f},{0.f,0.f,0.f,0.f}};
      #pragma unroll
      for (int s = 0; s < 2; ++s)
        #pragma unroll
        for (int f = 0; f < 2; ++f)
          sacc[f] = __builtin_amdgcn_mfma_f32_16x16x32_bf16(bk[f][s], aq[s], sacc[f], 0, 0, 0);

      // p = exp2(s) * rl  (lane owns q = l15; k = qt*256 + kt*32 + f*16 + lg*4 + r)
      f32x4 pv[2];
      #pragma unroll
      for (int f = 0; f < 2; ++f)
        #pragma unroll
        for (int r = 0; r < 4; ++r)
          pv[f][r] = EXP2(sacc[f][r]) * rl;

      // attn stores straight from registers
      float* arow = attnb + (size_t)l15 * LL + qt * 256 + kt * 32 + lg * 4;
      *(f32x4*)(arow)      = pv[0];
      *(f32x4*)(arow + 16) = pv[1];

      // PV A-operand through wave-private bf16 LDS (layout shuffle only)
      #pragma unroll
      for (int f = 0; f < 2; ++f) {
        bf16x4 pb;
        #pragma unroll
        for (int r = 0; r < 4; ++r) pb[r] = (__bf16)pv[f][r];
        *(bf16x4*)(prow + f * 16 + lg * 4) = pb;
      }
      bf16x8 pa = *(const bf16x8*)(prow + lg * 8);
      #pragma unroll
      for (int g = 0; g < 4; ++g)
        cacc[g] = __builtin_amdgcn_mfma_f32_16x16x32_bf16(pa, bv[g], cacc[g], 0, 0, 0);
    }
  }

  // ---- context epilogue ----
  #pragma unroll
  for (int g = 0; g < 4; ++g)
    #pragma unroll
    for (int r = 0; r < 4; ++r)
      ctxb[(size_t)(lg * 4 + r) * DD + g * 16 + l15] = cacc[g][r];
}

// ====================== fallback (R1 kernel, proven) ========================
#define BQ 64
#define BK 32
#define KSTRIDE 72
#define VSTRIDE 40
#define PSTRIDE 48

__global__ __launch_bounds__(256, 4)
void sdpa_fallback(const float* __restrict__ q, const float* __restrict__ k,
                   const float* __restrict__ v, const float* __restrict__ scale_p,
                   float* __restrict__ out) {
  const int tid  = threadIdx.x;
  const int lane = tid & 63;
  const int w    = tid >> 6;
  int bid = blockIdx.x;
  bid = (bid & 7) * 128 + (bid >> 3);
  const int b    = bid >> 4;
  const int qblk = (bid & 15) * BQ;

  __shared__ __bf16 Ks[BK * KSTRIDE];
  __shared__ __bf16 Vs[DD * VSTRIDE];
  __shared__ __bf16 Pp[4][16 * PSTRIDE];

  const float scale = scale_p[0];
  const float* qb = q + ((size_t)b * LL + qblk) * DD;
  const float* kb = k + (size_t)b * LL * DD;
  const float* vb = v + (size_t)b * LL * DD;
  float* ctx  = out + ((size_t)b * LL + qblk) * DD;
  float* attn = out + (size_t)NB * LL * DD + (size_t)b * LL * LL + (size_t)qblk * LL;

  const int l15 = lane & 15;
  const int lg  = lane >> 4;
  const int dchunk = lg * 8;

  bf16x8 aq[2];
  {
    const float* qrow = qb + (size_t)(w * 16 + l15) * DD;
    #pragma unroll
    for (int s = 0; s < 2; ++s) {
      const f32x4* p4 = (const f32x4*)(qrow + s * 32 + dchunk);
      f32x4 x0 = p4[0], x1 = p4[1];
      #pragma unroll
      for (int j = 0; j < 4; ++j) {
        aq[s][j]     = (__bf16)(x0[j] * scale);
        aq[s][4 + j] = (__bf16)(x1[j] * scale);
      }
    }
  }

  const int srow = tid >> 3;
  const int sd0  = (tid & 7) * 8;

  float lpart[4] = {0.f, 0.f, 0.f, 0.f};
  for (int kt = 0; kt < LL / BK; ++kt) {
    __syncthreads();
    {
      const f32x4* src = (const f32x4*)(kb + (size_t)(kt * BK + srow) * DD + sd0);
      f32x4 x0 = src[0], x1 = src[1];
      bf16x8 t;
      #pragma unroll
      for (int j = 0; j < 4; ++j) { t[j] = (__bf16)x0[j]; t[4 + j] = (__bf16)x1[j]; }
      *(bf16x8*)&Ks[srow * KSTRIDE + sd0] = t;
    }
    __syncthreads();
    f32x4 sacc[2] = {{0.f,0.f,0.f,0.f},{0.f,0.f,0.f,0.f}};
    #pragma unroll
    for (int s = 0; s < 2; ++s)
      #pragma unroll
      for (int f = 0; f < 2; ++f) {
        bf16x8 bk = *(const bf16x8*)&Ks[(f * 16 + l15) * KSTRIDE + s * 32 + dchunk];
        sacc[f] = __builtin_amdgcn_mfma_f32_16x16x32_bf16(aq[s], bk, sacc[f], 0, 0, 0);
      }
    #pragma unroll
    for (int f = 0; f < 2; ++f)
      #pragma unroll
      for (int r = 0; r < 4; ++r)
        lpart[r] += __expf(sacc[f][r]);
  }
  #pragma unroll
  for (int m = 1; m < 16; m <<= 1)
    #pragma unroll
    for (int r = 0; r < 4; ++r)
      lpart[r] += __shfl_xor(lpart[r], m, 64);
  float rl[4];
  #pragma unroll
  for (int r = 0; r < 4; ++r) rl[r] = 1.0f / lpart[r];

  f32x4 cacc[4] = {{0.f,0.f,0.f,0.f},{0.f,0.f,0.f,0.f},
                   {0.f,0.f,0.f,0.f},{0.f,0.f,0.f,0.f}};
  for (int kt = 0; kt < LL / BK; ++kt) {
    __syncthreads();
    {
      const f32x4* src = (const f32x4*)(kb + (size_t)(kt * BK + srow) * DD + sd0);
      f32x4 x0 = src[0], x1 = src[1];
      bf16x8 t;
      #pragma unroll
      for (int j = 0; j < 4; ++j) { t[j] = (__bf16)x0[j]; t[4 + j] = (__bf16)x1[j]; }
      *(bf16x8*)&Ks[srow * KSTRIDE + sd0] = t;
      const f32x4* vsrc = (const f32x4*)(vb + (size_t)(kt * BK + srow) * DD + sd0);
      f32x4 y0 = vsrc[0], y1 = vsrc[1];
      #pragma unroll
      for (int j = 0; j < 4; ++j) {
        Vs[(sd0 + j)     * VSTRIDE + srow] = (__bf16)y0[j];
        Vs[(sd0 + 4 + j) * VSTRIDE + srow] = (__bf16)y1[j];
      }
    }
    __syncthreads();
    f32x4 sacc[2] = {{0.f,0.f,0.f,0.f},{0.f,0.f,0.f,0.f}};
    #pragma unroll
    for (int s = 0; s < 2; ++s)
      #pragma unroll
      for (int f = 0; f < 2; ++f) {
        bf16x8 bk = *(const bf16x8*)&Ks[(f * 16 + l15) * KSTRIDE + s * 32 + dchunk];
        sacc[f] = __builtin_amdgcn_mfma_f32_16x16x32_bf16(aq[s], bk, sacc[f], 0, 0, 0);
      }
    #pragma unroll
    for (int f = 0; f < 2; ++f)
      #pragma unroll
      for (int r = 0; r < 4; ++r) {
        const int row = lg * 4 + r;
        float p = __expf(sacc[f][r]) * rl[r];
        attn[(size_t)(w * 16 + row) * LL + (kt * BK + f * 16 + l15)] = p;
        Pp[w][row * PSTRIDE + f * 16 + l15] = (__bf16)p;
      }
    bf16x8 pa = *(const bf16x8*)&Pp[w][l15 * PSTRIDE + lg * 8];
    #pragma unroll
    for (int g = 0; g < 4; ++g) {
      bf16x8 bv = *(const bf16x8*)&Vs[(g * 16 + l15) * VSTRIDE + lg * 8];
      cacc[g] = __builtin_amdgcn_mfma_f32_16x16x32_bf16(pa, bv, cacc[g], 0, 0, 0);
    }
  }
  #pragma unroll
  for (int g = 0; g < 4; ++g)
    #pragma unroll
    for (int r = 0; r < 4; ++r)
      ctx[(size_t)(w * 16 + lg * 4 + r) * DD + g * 16 + l15] = cacc[g][r];
}

extern "C" void kernel_launch(void* const* d_in, const int* in_sizes, int n_in,
                              void* d_out, int out_size, void* d_ws, size_t ws_size,
                              hipStream_t stream) {
  const float* q = (const float*)d_in[0];
  const float* k = (const float*)d_in[1];
  const float* v = (const float*)d_in[2];
  const float* s = (const float*)d_in[3];
  float* out = (float*)d_out;

  if (ws_size >= WS_NEED) {
    __bf16* vt  = (__bf16*)((char*)d_ws + WS_VT_OFF);
    __bf16* kbf = (__bf16*)((char*)d_ws + WS_KB_OFF);
    preconvert_kv<<<dim3(3072), dim3(256), 0, stream>>>(k, v, kbf, vt);
    sdpa_quarter<<<dim3(1024), dim3(256), 0, stream>>>(q, kbf, vt, s, out);
  } else {
    sdpa_fallback<<<dim3(NB * (LL / 64)), dim3(256), 0, stream>>>(q, k, v, s, out);
  }
}